// Round 1
// 1076.704 us; speedup vs baseline: 1.5337x; 1.5337x over previous
//
#include <hip/hip_runtime.h>

// ---------------------------------------------------------------------------
// FullTensorProductSparse: irreps1 = 32x(l=0,1,2), irreps2 = 1x(l=0,1,2)
// input1: (N,288), chunk element index = off1 + m*32 + u   (off1 in {0,32,128})
// input2: (N,9), offsets {0,1,4}
// output: (N,2592), e3nn-sorted chunk order (POSTART below)
//
// This version:
//  * CG tables generated at COMPILE TIME (constexpr Racah + real-SH basis
//    change) -> no init_kernel dispatch at all.
//  * One wave processes 2 rows (lanes 0-31 row A, lanes 32-63 row B):
//    u = lane&31, full 64-lane utilization, zero divergence, all path
//    dims are template constants (fully unrolled, CG folded to literals,
//    exact-zero CG terms eliminated at compile time).
//  * x1 read exactly once per element via coalesced global loads, reused in
//    registers across all chunks sharing the same l1. No barriers.
//  * Outputs staged per-wave in a private 2.3KB LDS slice (odd-d3 scatter is
//    bank-conflict-free), then written as fully-coalesced float4 stores.
// ---------------------------------------------------------------------------

namespace cgc {

struct Cplx { double r, i; };

constexpr double CFACT[14] = {
  1.0, 1.0, 2.0, 6.0, 24.0, 120.0, 720.0, 5040.0, 40320.0, 362880.0,
  3628800.0, 39916800.0, 479001600.0, 6227020800.0 };

constexpr double csqrt(double x){
  if (x <= 0.0) return 0.0;
  double g = x < 1.0 ? 1.0 : x;
  for (int i = 0; i < 32; ++i) g = 0.5 * (g + x / g);
  return g;
}

constexpr double su2_cg(int j1,int m1,int j2,int m2,int j3,int m3){
  if (m3 != m1 + m2) return 0.0;
  int vmin = -j1 + j2 + m3;
  if (-j1 + m1 > vmin) vmin = -j1 + m1;
  if (0 > vmin) vmin = 0;
  int vmax = j2 + j3 + m1;
  if (j3 - j1 + j2 < vmax) vmax = j3 - j1 + j2;
  if (j3 + m3 < vmax) vmax = j3 + m3;
  if (vmax < vmin) return 0.0;
  const double C = csqrt((2.0*j3 + 1.0) * CFACT[j3+j1-j2] * CFACT[j3-j1+j2] * CFACT[j1+j2-j3]
                         * CFACT[j3+m3] * CFACT[j3-m3]
                         / (CFACT[j1+j2+j3+1] * CFACT[j1-m1] * CFACT[j1+m1]
                            * CFACT[j2-m2] * CFACT[j2+m2]));
  double S = 0.0;
  for (int v = vmin; v <= vmax; ++v){
    const double t = CFACT[j2+j3+m1-v] * CFACT[j1-m1+v]
                   / (CFACT[v] * CFACT[j3-j1+j2-v] * CFACT[j3+m3-v] * CFACT[v+j1-j2-m3]);
    S += ((v + j2 + m2) & 1) ? -t : t;
  }
  return C * S;
}

// entry (row, col) of real->complex SH change-of-basis q(l), e3nn convention
constexpr Cplx qent(int l,int row,int col){
  double br = 0.0, bi = 0.0;
  const double s = 0.70710678118654752440;
  const int m = row - l;
  if (m < 0){
    if (col == l - m) br = s;
    else if (col == l + m) bi = -s;
  } else if (m == 0){
    if (col == l) br = 1.0;
  } else {
    const double sg = (m & 1) ? -1.0 : 1.0;
    if (col == l + m) br = sg * s;
    else if (col == l - m) bi = sg * s;
  }
  double pr = 1.0, pi = 0.0;
  switch (l & 3){                       // multiply by (-i)^l
    case 0: pr = 1.0;  pi = 0.0;  break;
    case 1: pr = 0.0;  pi = -1.0; break;
    case 2: pr = -1.0; pi = 0.0;  break;
    default: pr = 0.0; pi = 1.0;  break;
  }
  return Cplx{ br*pr - bi*pi, br*pi + bi*pr };
}

constexpr int PL1[19]  = {0,0,0,1,1,1,1,1,1,1,2,2,2,2,2,2,2,2,2};
constexpr int PL2[19]  = {0,1,2,0,1,1,1,2,2,2,0,1,1,1,4/2,2,2,2,2};  // (note: 4/2==2)
constexpr int PL3[19]  = {0,1,2,1,0,1,2,1,2,3,2,1,2,3,0,1,2,3,4};
constexpr int PX2O[19] = {0,1,4,0,1,1,1,4,4,4,0,1,1,1,4,4,4,4,4};
// output chunk start per PATH index (from e3nn sort order of (l3, -p*(-1)^l3)):
constexpr int POSTART[19] = {0,96,672,192,32,480,832,288,1312,1632,
                             992,384,1472,1856,64,576,1152,2080,2304};

struct PathCGf { float v[225]; };

template<int P>
constexpr PathCGf make_cgf(){
  const int l1 = PL1[P], l2 = PL2[P], l3 = PL3[P];
  const int d1 = 2*l1+1, d2 = 2*l2+1, d3 = 2*l3+1;
  double tmp[225] = {};
  for (int m = 0; m < d1; ++m)
    for (int n = 0; n < d2; ++n)
      for (int o = 0; o < d3; ++o){
        double acc = 0.0;
        for (int i = 0; i < d1; ++i){
          const Cplx q1 = qent(l1, i, m);
          if (q1.r == 0.0 && q1.i == 0.0) continue;
          for (int k = 0; k < d2; ++k){
            const Cplx q2 = qent(l2, k, n);
            if (q2.r == 0.0 && q2.i == 0.0) continue;
            const int mm = l3 + (i - l1) + (k - l2);   // only m3-matching term
            if (mm < 0 || mm >= d3) continue;
            const Cplx q3 = qent(l3, mm, o);
            if (q3.r == 0.0 && q3.i == 0.0) continue;
            const double w = su2_cg(l1, i-l1, l2, k-l2, l3, mm-l3);
            if (w == 0.0) continue;
            const double ar = q1.r*q2.r - q1.i*q2.i;
            const double ai = q1.r*q2.i + q1.i*q2.r;
            acc += (ar*q3.r + ai*q3.i) * w;            // real((q1*q2)*conj(q3))*cg
          }
        }
        tmp[(m*d2 + n)*d3 + o] = acc;
      }
  double s2 = 0.0;
  for (int j = 0; j < d1*d2*d3; ++j) s2 += tmp[j]*tmp[j];
  const double scale = csqrt((double)(2*l3+1)) / csqrt(s2);
  PathCGf f{};
  for (int j = 0; j < d1*d2*d3; ++j) f.v[j] = (float)(tmp[j] * scale);
  return f;
}

// 19 separate constexpr vars: keeps each initializer well under the
// per-variable constexpr-step limit.
constexpr PathCGf CG0  = make_cgf<0>();
constexpr PathCGf CG1  = make_cgf<1>();
constexpr PathCGf CG2  = make_cgf<2>();
constexpr PathCGf CG3  = make_cgf<3>();
constexpr PathCGf CG4  = make_cgf<4>();
constexpr PathCGf CG5  = make_cgf<5>();
constexpr PathCGf CG6  = make_cgf<6>();
constexpr PathCGf CG7  = make_cgf<7>();
constexpr PathCGf CG8  = make_cgf<8>();
constexpr PathCGf CG9  = make_cgf<9>();
constexpr PathCGf CG10 = make_cgf<10>();
constexpr PathCGf CG11 = make_cgf<11>();
constexpr PathCGf CG12 = make_cgf<12>();
constexpr PathCGf CG13 = make_cgf<13>();
constexpr PathCGf CG14 = make_cgf<14>();
constexpr PathCGf CG15 = make_cgf<15>();
constexpr PathCGf CG16 = make_cgf<16>();
constexpr PathCGf CG17 = make_cgf<17>();
constexpr PathCGf CG18 = make_cgf<18>();

template<int P>
__host__ __device__ constexpr float cgv(int m, int n, int o){
  const int idx = (m*(2*PL2[P]+1) + n)*(2*PL3[P]+1) + o;
  if constexpr (P == 0)  return CG0.v[idx];
  else if constexpr (P == 1)  return CG1.v[idx];
  else if constexpr (P == 2)  return CG2.v[idx];
  else if constexpr (P == 3)  return CG3.v[idx];
  else if constexpr (P == 4)  return CG4.v[idx];
  else if constexpr (P == 5)  return CG5.v[idx];
  else if constexpr (P == 6)  return CG6.v[idx];
  else if constexpr (P == 7)  return CG7.v[idx];
  else if constexpr (P == 8)  return CG8.v[idx];
  else if constexpr (P == 9)  return CG9.v[idx];
  else if constexpr (P == 10) return CG10.v[idx];
  else if constexpr (P == 11) return CG11.v[idx];
  else if constexpr (P == 12) return CG12.v[idx];
  else if constexpr (P == 13) return CG13.v[idx];
  else if constexpr (P == 14) return CG14.v[idx];
  else if constexpr (P == 15) return CG15.v[idx];
  else if constexpr (P == 16) return CG16.v[idx];
  else if constexpr (P == 17) return CG17.v[idx];
  else return CG18.v[idx];
}

template<int P>
__host__ __device__ constexpr bool wnz(int m, int o){
  for (int n = 0; n < 2*PL2[P]+1; ++n)
    if (cgv<P>(m, n, o) != 0.0f) return true;
  return false;
}

} // namespace cgc

// ---------------------------------------------------------------------------
// Per-path chunk: compute w[m][o] in registers from folded CG constants,
// dot with register-held x1 column, transpose via per-wave LDS slice,
// store as coalesced float4.
// lane 0-31: row row2 (u=lane), lane 32-63: row row2+1 (u=lane-32).
// ---------------------------------------------------------------------------
template<int P>
__device__ __forceinline__ void chunk_op(const float* __restrict__ a,
                                         const float (&x2v)[9],
                                         float* __restrict__ lbuf,
                                         float* __restrict__ outp,
                                         int lane, int row2, int N){
  constexpr int D1  = 2*cgc::PL1[P] + 1;
  constexpr int D2  = 2*cgc::PL2[P] + 1;
  constexpr int D3  = 2*cgc::PL3[P] + 1;
  constexpr int X2O = cgc::PX2O[P];
  constexpr int OST = cgc::POSTART[P];

  // WAR guard: previous chunk's cross-lane ds_reads must drain before we
  // overwrite the wave's LDS slice. (Same-wave DS ops + lgkmcnt(0).)
  asm volatile("s_waitcnt lgkmcnt(0)" ::: "memory");

  const int wb = lane * D3;                 // odd D3 -> conflict-free scatter
  #pragma unroll
  for (int o = 0; o < D3; ++o){
    float acc = 0.f;
    #pragma unroll
    for (int m = 0; m < D1; ++m){
      if (cgc::wnz<P>(m, o)){
        float wm = 0.f;
        #pragma unroll
        for (int n = 0; n < D2; ++n){
          const float c = cgc::cgv<P>(m, n, o);   // folds to a literal
          if (c != 0.f) wm += c * x2v[X2O + n];   // zero terms vanish
        }
        acc += a[m] * wm;
      }
    }
    lbuf[wb + o] = acc;
  }

  // cross-lane RAW: writes above must be visible to the transposed reads
  asm volatile("s_waitcnt lgkmcnt(0)" ::: "memory");

  constexpr int NF4 = 16 * D3;              // float4 count for the 2 rows
  #pragma unroll
  for (int p = 0; p < (NF4 + 63)/64; ++p){
    const int f = p*64 + lane;
    if (f < NF4){
      const int rr  = (f >= 8*D3) ? 1 : 0;  // which of the 2 rows
      const int idx = f - rr*8*D3;
      if (row2 + rr < N){
        const float4 val = *reinterpret_cast<const float4*>(lbuf + 4*f);
        *reinterpret_cast<float4*>(outp + (size_t)rr*2592 + OST + 4*idx) = val;
      }
    }
  }
}

__global__ __launch_bounds__(256) void tp_kernel(const float* __restrict__ x1,
                                                 const float* __restrict__ x2,
                                                 float* __restrict__ out, int N){
  __shared__ __align__(16) float lds[4][576];   // 2.3KB private slice per wave
  const int wv   = threadIdx.x >> 6;
  const int lane = threadIdx.x & 63;
  const int u    = lane & 31;
  const int half = lane >> 5;
  float* lbuf = lds[wv];
  const int wstep = gridDim.x * 4;

  for (int w = blockIdx.x*4 + wv; 2*w < N; w += wstep){
    const int row2 = 2*w;
    int row = row2 + half;
    if (row >= N) row = N - 1;                  // clamp (stores are guarded)
    const float* __restrict__ x1r = x1 + (size_t)row * 288;
    const float* __restrict__ x2r = x2 + (size_t)row * 9;
    float* __restrict__ outp = out + (size_t)row2 * 2592;

    float x2v[9];
    #pragma unroll
    for (int n = 0; n < 9; ++n) x2v[n] = x2r[n];

    // l1 = 0 chunk column (1 value), paths 0..2
    float aL0[1];
    aL0[0] = x1r[u];
    chunk_op<0>(aL0, x2v, lbuf, outp, lane, row2, N);
    chunk_op<1>(aL0, x2v, lbuf, outp, lane, row2, N);
    chunk_op<2>(aL0, x2v, lbuf, outp, lane, row2, N);

    // l1 = 1 chunk column (3 values), paths 3..9
    float aL1[3];
    #pragma unroll
    for (int m = 0; m < 3; ++m) aL1[m] = x1r[32 + m*32 + u];
    chunk_op<3>(aL1, x2v, lbuf, outp, lane, row2, N);
    chunk_op<4>(aL1, x2v, lbuf, outp, lane, row2, N);
    chunk_op<5>(aL1, x2v, lbuf, outp, lane, row2, N);
    chunk_op<6>(aL1, x2v, lbuf, outp, lane, row2, N);
    chunk_op<7>(aL1, x2v, lbuf, outp, lane, row2, N);
    chunk_op<8>(aL1, x2v, lbuf, outp, lane, row2, N);
    chunk_op<9>(aL1, x2v, lbuf, outp, lane, row2, N);

    // l1 = 2 chunk column (5 values), paths 10..18
    float aL2[5];
    #pragma unroll
    for (int m = 0; m < 5; ++m) aL2[m] = x1r[128 + m*32 + u];
    chunk_op<10>(aL2, x2v, lbuf, outp, lane, row2, N);
    chunk_op<11>(aL2, x2v, lbuf, outp, lane, row2, N);
    chunk_op<12>(aL2, x2v, lbuf, outp, lane, row2, N);
    chunk_op<13>(aL2, x2v, lbuf, outp, lane, row2, N);
    chunk_op<14>(aL2, x2v, lbuf, outp, lane, row2, N);
    chunk_op<15>(aL2, x2v, lbuf, outp, lane, row2, N);
    chunk_op<16>(aL2, x2v, lbuf, outp, lane, row2, N);
    chunk_op<17>(aL2, x2v, lbuf, outp, lane, row2, N);
    chunk_op<18>(aL2, x2v, lbuf, outp, lane, row2, N);
  }
}

extern "C" void kernel_launch(void* const* d_in, const int* in_sizes, int n_in,
                              void* d_out, int out_size, void* d_ws, size_t ws_size,
                              hipStream_t stream) {
  (void)n_in; (void)out_size; (void)d_ws; (void)ws_size;
  const float* x1 = (const float*)d_in[0];
  const float* x2 = (const float*)d_in[1];
  float* out = (float*)d_out;
  int N = in_sizes[0] / 288;   // 100000
  if (N <= 0) N = 1;

  int grid = (N + 7) / 8;      // 4 waves/block x 2 rows/wave
  hipLaunchKernelGGL(tp_kernel, dim3(grid), dim3(256), 0, stream, x1, x2, out, N);
}